// Round 1
// baseline (50.160 us; speedup 1.0000x reference)
//
#include <hip/hip_runtime.h>
#include <hip/hip_bf16.h>

// CrossSigmoidFocalLoss: mean over (N,C) of
//   focal_w * bce * row_w * cross_mask
// with focal_w = (a*onehot + (1-a)*(1-onehot)) * pt^gamma, gamma=2, a=0.25
//      pt = onehot*(1-p) + (1-onehot)*p,  p = sigmoid(pred)
//      bce = onehot*softplus(-x) + (1-onehot)*softplus(x)
//      row_w = weight>0 ? 1 : 0
//      cross_mask = (t==C) ? bit_c(int(weight)) : 1   (bits >= 16 are 0 since weight < 2^16)
//
// Folded form: y = (c==t) ? -x : x ; term = (c==t?0.25:0.75) * sigmoid(y)^2 * softplus(y)

#define NCLS 80
#define C4   (NCLS / 4)   // 20 float4 per row

__device__ __forceinline__ float focal_term(float x, bool pos) {
    const float y = pos ? -x : x;
    const float a = pos ? 0.25f : 0.75f;
    const float e = __expf(-fabsf(y));        // exp(-|y|), in (0,1]
    const float inv = __frcp_rn(1.0f + e);    // 1/(1+e)
    const float s = (y >= 0.0f) ? inv : e * inv;            // sigmoid(y)
    const float sp = fmaxf(y, 0.0f) + __logf(1.0f + e);     // softplus(y), stable
    return a * s * s * sp;
}

__global__ void __launch_bounds__(256)
cfs_kernel(const float* __restrict__ pred,
           const int*   __restrict__ targets,
           const float* __restrict__ weight,
           float* __restrict__ out,
           int total4, float inv_total) {
    const int tid    = blockIdx.x * blockDim.x + threadIdx.x;
    const int stride = gridDim.x * blockDim.x;

    float acc = 0.0f;
    for (int i = tid; i < total4; i += stride) {
        const int n  = i / C4;              // row  (constant divide -> magic mul)
        const int r  = i - n * C4;
        const int c0 = r * 4;               // first class of this float4

        const float wf = weight[n];
        if (wf <= 0.0f) continue;           // row weight binarized to 0 -> no contribution
        const int t = targets[n];

        if (t == NCLS) {
            // negative/background row: one-hot all zero, mask by schema bits.
            // weight < 2^16 so bits for c >= 32 (and >= 16) are zero -> skip.
            if (c0 >= 32) continue;
            const float4 x4 = reinterpret_cast<const float4*>(pred)[i];
            const int wi = (int)wf;
            if ((wi >> (c0 + 0)) & 1) acc += focal_term(x4.x, false);
            if ((wi >> (c0 + 1)) & 1) acc += focal_term(x4.y, false);
            if ((wi >> (c0 + 2)) & 1) acc += focal_term(x4.z, false);
            if ((wi >> (c0 + 3)) & 1) acc += focal_term(x4.w, false);
        } else {
            const float4 x4 = reinterpret_cast<const float4*>(pred)[i];
            acc += focal_term(x4.x, t == c0 + 0);
            acc += focal_term(x4.y, t == c0 + 1);
            acc += focal_term(x4.z, t == c0 + 2);
            acc += focal_term(x4.w, t == c0 + 3);
        }
    }

    // wave (64-lane) reduction
    #pragma unroll
    for (int off = 32; off > 0; off >>= 1)
        acc += __shfl_down(acc, off, 64);

    __shared__ float smem[4];
    const int lane = threadIdx.x & 63;
    const int wid  = threadIdx.x >> 6;
    if (lane == 0) smem[wid] = acc;
    __syncthreads();
    if (threadIdx.x == 0) {
        const float v = smem[0] + smem[1] + smem[2] + smem[3];
        atomicAdd(out, v * inv_total);
    }
}

extern "C" void kernel_launch(void* const* d_in, const int* in_sizes, int n_in,
                              void* d_out, int out_size, void* d_ws, size_t ws_size,
                              hipStream_t stream) {
    const float* pred    = (const float*)d_in[0];
    const int*   targets = (const int*)  d_in[1];
    const float* weight  = (const float*)d_in[2];
    float*       out     = (float*)d_out;

    const int n_rows = in_sizes[1];          // 262144
    const int total4 = n_rows * C4;          // 5,242,880 float4 elements
    const float inv_total = 1.0f / (float)(n_rows * NCLS);

    // zero the scalar accumulator (harness poisons d_out, does not re-poison between replays)
    hipMemsetAsync(d_out, 0, sizeof(float), stream);

    const int threads = 256;
    int blocks = (total4 + threads - 1) / threads;
    if (blocks > 2048) blocks = 2048;        // grid-stride; 2048 blocks = 8 wg/CU
    cfs_kernel<<<blocks, threads, 0, stream>>>(pred, targets, weight, out, total4, inv_total);
}

// Round 4
// 32.751 us; speedup vs baseline: 1.5316x; 1.5316x over previous
//
#include <hip/hip_runtime.h>
#include <hip/hip_bf16.h>

// CrossSigmoidFocalLoss: mean over (N,C) of focal_w * bce * row_w * cross_mask
// Folded per-element form (y = (c==t) ? -x : x):
//   term = (c==t ? 0.25 : 0.75) * sigmoid(y)^2 * softplus(y) * mask
//   mask = row_w(weight>0) * (t==C ? bit_c(int(weight)) : 1)
// weight < 2^16, so schema bits for c >= 16 are zero (c >= 32 handled explicitly).

#define NCLS 80
#define C4   (NCLS / 4)   // 20 float4 per row
#define NBLOCKS 2048
#define NTHREADS 256

__device__ __forceinline__ float elem_term(float x, int c, int t, int wi, bool neg) {
    const bool  pos = (c == t);
    // schema bit for negative rows; 0 for c >= 32 (and bits 16..31 of wi are 0 anyway)
    const int   bit = (c < 32) ? ((wi >> c) & 1) : 0;
    const float m   = neg ? (float)bit : 1.0f;
    const float a   = pos ? 0.25f : 0.75f;
    const float y   = pos ? -x : x;
    const float e   = __expf(-fabsf(y));                   // v_exp_f32 path, e in (0,1]
    const float inv = __builtin_amdgcn_rcpf(1.0f + e);     // raw v_rcp_f32 (approx)
    const float s   = (y >= 0.0f) ? inv : e * inv;         // sigmoid(y)
    const float sp  = fmaxf(y, 0.0f) + __logf(1.0f + e);   // softplus(y), stable
    return (a * m) * s * s * sp;
}

__global__ void __launch_bounds__(NTHREADS)
cfs_main(const float* __restrict__ pred,
         const int*   __restrict__ targets,
         const float* __restrict__ weight,
         float* __restrict__ partials,
         int total4) {
    const int tid    = blockIdx.x * blockDim.x + threadIdx.x;
    const int stride = gridDim.x * blockDim.x;

    float acc = 0.0f;
    for (int i = tid; i < total4; i += stride) {
        const int n  = i / C4;              // row (magic-mul divide)
        const int r  = i - n * C4;
        const int c0 = r * 4;

        const float4 x4 = reinterpret_cast<const float4*>(pred)[i];
        const int    t  = targets[n];
        const float  wf = weight[n];
        const int    wi = (int)wf;
        const bool  neg = (t == NCLS);
        const float  rw = (wf > 0.0f) ? 1.0f : 0.0f;

        const float s4 = elem_term(x4.x, c0 + 0, t, wi, neg)
                       + elem_term(x4.y, c0 + 1, t, wi, neg)
                       + elem_term(x4.z, c0 + 2, t, wi, neg)
                       + elem_term(x4.w, c0 + 3, t, wi, neg);
        acc = __builtin_fmaf(rw, s4, acc);
    }

    // wave (64-lane) reduction
    #pragma unroll
    for (int off = 32; off > 0; off >>= 1)
        acc += __shfl_down(acc, off, 64);

    __shared__ float smem[NTHREADS / 64];
    const int lane = threadIdx.x & 63;
    const int wid  = threadIdx.x >> 6;
    if (lane == 0) smem[wid] = acc;
    __syncthreads();
    if (threadIdx.x == 0) {
        float v = 0.0f;
        #pragma unroll
        for (int w = 0; w < NTHREADS / 64; ++w) v += smem[w];
        partials[blockIdx.x] = v;           // plain store, no atomics
    }
}

__global__ void __launch_bounds__(NTHREADS)
cfs_reduce(const float* __restrict__ partials, float* __restrict__ out,
           int nparts, float scale) {
    float acc = 0.0f;
    for (int i = threadIdx.x; i < nparts; i += NTHREADS)
        acc += partials[i];
    #pragma unroll
    for (int off = 32; off > 0; off >>= 1)
        acc += __shfl_down(acc, off, 64);

    __shared__ float smem[NTHREADS / 64];
    const int lane = threadIdx.x & 63;
    const int wid  = threadIdx.x >> 6;
    if (lane == 0) smem[wid] = acc;
    __syncthreads();
    if (threadIdx.x == 0) {
        float v = 0.0f;
        #pragma unroll
        for (int w = 0; w < NTHREADS / 64; ++w) v += smem[w];
        out[0] = v * scale;                 // unconditional write each launch
    }
}

extern "C" void kernel_launch(void* const* d_in, const int* in_sizes, int n_in,
                              void* d_out, int out_size, void* d_ws, size_t ws_size,
                              hipStream_t stream) {
    const float* pred    = (const float*)d_in[0];
    const int*   targets = (const int*)  d_in[1];
    const float* weight  = (const float*)d_in[2];
    float*       out     = (float*)d_out;
    float*       partials = (float*)d_ws;   // NBLOCKS floats of scratch

    const int n_rows = in_sizes[1];          // 262144
    const int total4 = n_rows * C4;          // 5,242,880
    const float inv_total = 1.0f / (float)(n_rows * NCLS);

    cfs_main<<<NBLOCKS, NTHREADS, 0, stream>>>(pred, targets, weight, partials, total4);
    cfs_reduce<<<1, NTHREADS, 0, stream>>>(partials, out, NBLOCKS, inv_total);
}

// Round 5
// 27.462 us; speedup vs baseline: 1.8265x; 1.1926x over previous
//
#include <hip/hip_runtime.h>
#include <hip/hip_bf16.h>

// CrossSigmoidFocalLoss: mean over (N,C) of focal_w * bce * row_w * cross_mask
// Folded per-element form (y = (c==t) ? -x : x):
//   term = (c==t ? 0.25 : 0.75) * sigmoid(y)^2 * softplus(y) * mask
//   mask = row_w(weight>0) * (t==C ? bit_c(int(weight)) : 1)
// weight < 2^16, so schema bits for c >= 16 are zero (c >= 32 handled explicitly).
// softplus(y) = max(y,0) + ln(1+e), e = exp(-|y|) in (0,1]; ln(1+e) via A&S 4.1.44
// degree-8 polynomial (|eps| <= 3e-8 on [0,1]) to drop one transcendental.

#define NCLS 80
#define C4   (NCLS / 4)   // 20 float4 per row
#define NBLOCKS 2048
#define NTHREADS 256
#define STRIDE (NBLOCKS * NTHREADS)   // 524288 threads

// ln(1+x) on [0,1], Abramowitz & Stegun 4.1.44 (|eps| <= 3e-8); sum(a_i)=ln2 exactly.
__device__ __forceinline__ float log1p_poly(float x) {
    float p = -0.0064535442f;
    p = __builtin_fmaf(p, x,  0.0360884937f);
    p = __builtin_fmaf(p, x, -0.0953293897f);
    p = __builtin_fmaf(p, x,  0.1676540711f);
    p = __builtin_fmaf(p, x, -0.2407338084f);
    p = __builtin_fmaf(p, x,  0.3317990258f);
    p = __builtin_fmaf(p, x, -0.4998741238f);
    p = __builtin_fmaf(p, x,  0.9999964239f);
    return p * x;
}

__device__ __forceinline__ float elem_term(float x, int c, int t, int wi, bool neg) {
    const bool  pos = (c == t);
    const int   bit = (c < 32) ? ((wi >> c) & 1) : 0;   // schema bit (0 for c>=16 anyway)
    const float m   = neg ? (float)bit : 1.0f;
    const float a   = pos ? 0.25f : 0.75f;
    const float y   = pos ? -x : x;
    const float e   = __expf(-fabsf(y));                 // v_exp_f32, e in (0,1]
    const float inv = __builtin_amdgcn_rcpf(1.0f + e);   // v_rcp_f32
    const float s   = (y >= 0.0f) ? inv : e * inv;       // sigmoid(y)
    const float sp  = fmaxf(y, 0.0f) + log1p_poly(e);    // softplus(y), stable
    return (a * m) * (s * s) * sp;
}

__device__ __forceinline__ float body(const float* __restrict__ pred,
                                      const int*   __restrict__ targets,
                                      const float* __restrict__ weight,
                                      int i) {
    const int n  = i / C4;              // magic-mul divide by 20
    const int r  = i - n * C4;
    const int c0 = r * 4;

    const float4 x4 = reinterpret_cast<const float4*>(pred)[i];
    const int    t  = targets[n];
    const float  wf = weight[n];
    const int    wi = (int)wf;
    const bool  neg = (t == NCLS);
    const float  rw = (wf > 0.0f) ? 1.0f : 0.0f;

    const float s4 = elem_term(x4.x, c0 + 0, t, wi, neg)
                   + elem_term(x4.y, c0 + 1, t, wi, neg)
                   + elem_term(x4.z, c0 + 2, t, wi, neg)
                   + elem_term(x4.w, c0 + 3, t, wi, neg);
    return rw * s4;
}

template<int KITERS>
__global__ void __launch_bounds__(NTHREADS)
cfs_main(const float* __restrict__ pred,
         const int*   __restrict__ targets,
         const float* __restrict__ weight,
         float* __restrict__ partials,
         int total4) {
    const int tid = blockIdx.x * NTHREADS + threadIdx.x;

    float acc = 0.0f;
    if constexpr (KITERS > 0) {
        // compile-time trip count: all loads issue up front, fully pipelined
        #pragma unroll
        for (int k = 0; k < KITERS; ++k)
            acc += body(pred, targets, weight, tid + k * STRIDE);
    } else {
        for (int i = tid; i < total4; i += STRIDE)
            acc += body(pred, targets, weight, i);
    }

    // wave (64-lane) reduction
    #pragma unroll
    for (int off = 32; off > 0; off >>= 1)
        acc += __shfl_down(acc, off, 64);

    __shared__ float smem[NTHREADS / 64];
    const int lane = threadIdx.x & 63;
    const int wid  = threadIdx.x >> 6;
    if (lane == 0) smem[wid] = acc;
    __syncthreads();
    if (threadIdx.x == 0) {
        float v = 0.0f;
        #pragma unroll
        for (int w = 0; w < NTHREADS / 64; ++w) v += smem[w];
        partials[blockIdx.x] = v;           // plain store, no atomics
    }
}

__global__ void __launch_bounds__(NTHREADS)
cfs_reduce(const float* __restrict__ partials, float* __restrict__ out,
           int nparts, float scale) {
    float acc = 0.0f;
    for (int i = threadIdx.x; i < nparts; i += NTHREADS)
        acc += partials[i];
    #pragma unroll
    for (int off = 32; off > 0; off >>= 1)
        acc += __shfl_down(acc, off, 64);

    __shared__ float smem[NTHREADS / 64];
    const int lane = threadIdx.x & 63;
    const int wid  = threadIdx.x >> 6;
    if (lane == 0) smem[wid] = acc;
    __syncthreads();
    if (threadIdx.x == 0) {
        float v = 0.0f;
        #pragma unroll
        for (int w = 0; w < NTHREADS / 64; ++w) v += smem[w];
        out[0] = v * scale;                 // unconditional overwrite each launch
    }
}

extern "C" void kernel_launch(void* const* d_in, const int* in_sizes, int n_in,
                              void* d_out, int out_size, void* d_ws, size_t ws_size,
                              hipStream_t stream) {
    const float* pred     = (const float*)d_in[0];
    const int*   targets  = (const int*)  d_in[1];
    const float* weight   = (const float*)d_in[2];
    float*       out      = (float*)d_out;
    float*       partials = (float*)d_ws;   // NBLOCKS floats of scratch

    const int n_rows = in_sizes[1];          // 262144
    const int total4 = n_rows * C4;          // 5,242,880
    const float inv_total = 1.0f / (float)(n_rows * NCLS);

    if (total4 == 10 * STRIDE) {
        cfs_main<10><<<NBLOCKS, NTHREADS, 0, stream>>>(pred, targets, weight, partials, total4);
    } else {
        cfs_main<0><<<NBLOCKS, NTHREADS, 0, stream>>>(pred, targets, weight, partials, total4);
    }
    cfs_reduce<<<1, NTHREADS, 0, stream>>>(partials, out, NBLOCKS, inv_total);
}